// Round 4
// baseline (112.312 us; speedup 1.0000x reference)
//
#include <hip/hip_runtime.h>

#define S 128
#define SS (S*S)
#define B 8
#define BSS (B*SS)              // 131072
#define NEG_INF (-3.402823466e+38f)

// ws layout (elements of 4B):
// [0..7]   topo loss accumulator (elem 0) + pad
// [8..31]  dice accumulators [b][{at,aa,tt}]
// [32 + idx*BSS + b*SS + ...] maps, idx:
//   0: Pb input (mapped uint, [j][k])   1: Pb target
//   2: Pc input (mapped uint, [i][k])   3: Pc target
//   4: Pa input (float, [i][j])         5: Pa target
#define ACC_LOSS 0
#define ACC_DICE 8
#define MAPS 32
#define MEMSET_BYTES ((size_t)(MAPS + 4*BSS) * 4)   // accs + Pb + Pc

__device__ __forceinline__ unsigned mapf(float f) {
  unsigned u = __float_as_uint(f);
  return (u & 0x80000000u) ? ~u : (u | 0x80000000u);
}
__device__ __forceinline__ float unmapf(unsigned u) {
  return (u & 0x80000000u) ? __uint_as_float(u & 0x7FFFFFFFu) : __uint_as_float(~u);
}
__device__ __forceinline__ float4 max4(float4 a, float4 b) {
  return make_float4(fmaxf(a.x,b.x), fmaxf(a.y,b.y), fmaxf(a.z,b.z), fmaxf(a.w,b.w));
}
__device__ __forceinline__ float hmax4(float4 a) {
  return fmaxf(fmaxf(a.x,a.y), fmaxf(a.z,a.w));
}
__device__ __forceinline__ float4 shflx4(float4 v, int m) {
  return make_float4(__shfl_xor(v.x,m,64), __shfl_xor(v.y,m,64),
                     __shfl_xor(v.z,m,64), __shfl_xor(v.w,m,64));
}

// Phase 1: stream channel-1 of both volumes once; projections + dice sums.
// Block = 8 i x 32 j x 128 k, 1024 threads: thread = (jr = tid>>5, kl = tid&31).
// Pc reduced via LDS in 2 rounds of 4 i's; tail uses all 1024 threads.
__global__ __launch_bounds__(1024, 8) void proj_dice_kernel(
    const float* __restrict__ gin, const float* __restrict__ gtg,
    float* __restrict__ ws)
{
  const int jc  = blockIdx.x;   // 0..3   j chunk of 32
  const int ic  = blockIdx.y;   // 0..15  i chunk of 8
  const int b   = blockIdx.z;   // 0..7
  const int tid = threadIdx.x;
  const int jr  = tid >> 5;     // 0..31
  const int kl  = tid & 31;     // 0..31
  const int j   = (jc << 5) + jr;
  const int i0  = ic << 3;
  const int k0  = kl << 2;
  const int w   = tid >> 6;     // wave 0..15
  const int h   = (tid >> 5) & 1;

  const float* __restrict__ xin = gin + (size_t)(2*b + 1) * (size_t)(S*SS);
  const float* __restrict__ xtg = gtg + (size_t)(2*b + 1) * (size_t)(S*SS);

  unsigned* pbI = (unsigned*)ws + MAPS + 0*BSS + (size_t)b*SS;
  unsigned* pbT = (unsigned*)ws + MAPS + 1*BSS + (size_t)b*SS;
  unsigned* pcI = (unsigned*)ws + MAPS + 2*BSS + (size_t)b*SS;
  unsigned* pcT = (unsigned*)ws + MAPS + 3*BSS + (size_t)b*SS;
  float*    paI = ws + MAPS + 4*BSS + (size_t)b*SS;
  float*    paT = ws + MAPS + 5*BSS + (size_t)b*SS;

  __shared__ float lpc[4][2][16][S];   // 64 KB: [ii][tensor][wave][k]
  __shared__ float dred[16][3];

  float4 pba = make_float4(NEG_INF, NEG_INF, NEG_INF, NEG_INF);
  float4 pbt = pba;
  float s_at = 0.f, s_aa = 0.f, s_tt = 0.f;

  for (int r = 0; r < 2; ++r) {
    #pragma unroll
    for (int q = 0; q < 4; ++q) {
      const int i = i0 + (r << 2) + q;
      const size_t off = (size_t)i*SS + (size_t)j*S + k0;
      const float4 a = *(const float4*)(xin + off);
      const float4 t = *(const float4*)(xtg + off);

      s_at = fmaf(a.x,t.x, fmaf(a.y,t.y, fmaf(a.z,t.z, fmaf(a.w,t.w, s_at))));
      s_aa = fmaf(a.x,a.x, fmaf(a.y,a.y, fmaf(a.z,a.z, fmaf(a.w,a.w, s_aa))));
      s_tt = fmaf(t.x,t.x, fmaf(t.y,t.y, fmaf(t.z,t.z, fmaf(t.w,t.w, s_tt))));

      // Pb accumulate over i
      pba = max4(pba, a);
      pbt = max4(pbt, t);

      // Pa[i][j]: max over k = 32 kl lanes of this half-wave
      float rma = hmax4(a), rmt = hmax4(t);
      #pragma unroll
      for (int m = 16; m >= 1; m >>= 1) {
        rma = fmaxf(rma, __shfl_xor(rma, m, 64));
        rmt = fmaxf(rmt, __shfl_xor(rmt, m, 64));
      }
      if (kl == 0) { paI[i*S + j] = rma; paT[i*S + j] = rmt; }

      // Pc wave partial: combine the wave's j-pair
      const float4 pca = max4(a, shflx4(a, 32));
      const float4 pct = max4(t, shflx4(t, 32));
      if (h == 0) {
        *(float4*)&lpc[q][0][w][k0] = pca;
        *(float4*)&lpc[q][1][w][k0] = pct;
      }
    }
    __syncthreads();
    {
      // tail: 1024 threads = 4 ii x 2 tensors x 128 k
      const int q  = tid >> 8;
      const int tt = (tid >> 7) & 1;
      const int k  = tid & 127;
      float m = lpc[q][tt][0][k];
      #pragma unroll
      for (int rr = 1; rr < 16; ++rr) m = fmaxf(m, lpc[q][tt][rr][k]);
      const int i = i0 + (r << 2) + q;
      atomicMax((tt ? pcT : pcI) + i*S + k, mapf(m));
    }
    if (r == 0) __syncthreads();
  }

  // flush Pb[j][k] (max over this block's 8 i's)
  atomicMax(pbI + j*S + k0+0, mapf(pba.x));
  atomicMax(pbI + j*S + k0+1, mapf(pba.y));
  atomicMax(pbI + j*S + k0+2, mapf(pba.z));
  atomicMax(pbI + j*S + k0+3, mapf(pba.w));
  atomicMax(pbT + j*S + k0+0, mapf(pbt.x));
  atomicMax(pbT + j*S + k0+1, mapf(pbt.y));
  atomicMax(pbT + j*S + k0+2, mapf(pbt.z));
  atomicMax(pbT + j*S + k0+3, mapf(pbt.w));

  // dice reduction
  float v0 = s_at, v1 = s_aa, v2 = s_tt;
  #pragma unroll
  for (int m = 32; m >= 1; m >>= 1) {
    v0 += __shfl_xor(v0, m, 64);
    v1 += __shfl_xor(v1, m, 64);
    v2 += __shfl_xor(v2, m, 64);
  }
  if ((tid & 63) == 0) { dred[w][0] = v0; dred[w][1] = v1; dred[w][2] = v2; }
  __syncthreads();
  if (tid == 0) {
    float a0 = 0.f, a1 = 0.f, a2 = 0.f;
    #pragma unroll
    for (int rr = 0; rr < 16; ++rr) { a0 += dred[rr][0]; a1 += dred[rr][1]; a2 += dred[rr][2]; }
    atomicAdd(ws + ACC_DICE + b*3 + 0, a0);
    atomicAdd(ws + ACC_DICE + b*3 + 1, a1);
    atomicAdd(ws + ACC_DICE + b*3 + 2, a2);
  }
}

// Phase 2: pyramid max-pool at all 5 scales in one pass.
// One block per batch b; thread grid 16x16, each thread owns an 8x8 tile.
__global__ __launch_bounds__(256) void pool_loss_kernel(float* __restrict__ ws)
{
  const int b   = blockIdx.x;
  const int tid = threadIdx.x;
  const int tr  = tid >> 4;
  const int tc  = tid & 15;
  const int r0  = tr << 3;
  const int c0  = tc << 3;

  float s2[2][4][4];
  float s4[2][2][2];
  float s8[2], s16[2], s32[2];
  #pragma unroll
  for (int v = 0; v < 2; ++v) {
    #pragma unroll
    for (int y = 0; y < 4; ++y)
      #pragma unroll
      for (int x = 0; x < 4; ++x) s2[v][y][x] = 0.f;
    #pragma unroll
    for (int y = 0; y < 2; ++y)
      #pragma unroll
      for (int x = 0; x < 2; ++x) s4[v][y][x] = 0.f;
    s8[v] = 0.f; s16[v] = 0.f; s32[v] = 0.f;
  }

  #pragma unroll
  for (int t = 0; t < 3; ++t) {
    #pragma unroll
    for (int vol = 0; vol < 2; ++vol) {
      const int idx = (t == 0) ? (4 + vol) : (t == 1) ? vol : (2 + vol);
      const size_t base = MAPS + (size_t)idx*BSS + (size_t)b*SS;
      float tile[8][8];
      if (t == 0) {
        const float* m = ws + base;
        #pragma unroll
        for (int r = 0; r < 8; ++r) {
          const float4 a = *(const float4*)(m + (size_t)(r0 + r)*S + c0);
          const float4 c = *(const float4*)(m + (size_t)(r0 + r)*S + c0 + 4);
          tile[r][0]=a.x; tile[r][1]=a.y; tile[r][2]=a.z; tile[r][3]=a.w;
          tile[r][4]=c.x; tile[r][5]=c.y; tile[r][6]=c.z; tile[r][7]=c.w;
        }
      } else {
        const unsigned* mu = (const unsigned*)ws + base;
        #pragma unroll
        for (int r = 0; r < 8; ++r) {
          const uint4 a = *(const uint4*)(mu + (size_t)(r0 + r)*S + c0);
          const uint4 c = *(const uint4*)(mu + (size_t)(r0 + r)*S + c0 + 4);
          tile[r][0]=unmapf(a.x); tile[r][1]=unmapf(a.y); tile[r][2]=unmapf(a.z); tile[r][3]=unmapf(a.w);
          tile[r][4]=unmapf(c.x); tile[r][5]=unmapf(c.y); tile[r][6]=unmapf(c.z); tile[r][7]=unmapf(c.w);
        }
      }
      float m2[4][4];
      #pragma unroll
      for (int y = 0; y < 4; ++y)
        #pragma unroll
        for (int x = 0; x < 4; ++x) {
          m2[y][x] = fmaxf(fmaxf(tile[2*y][2*x], tile[2*y][2*x+1]),
                           fmaxf(tile[2*y+1][2*x], tile[2*y+1][2*x+1]));
          s2[vol][y][x] += m2[y][x];
        }
      float m4[2][2];
      #pragma unroll
      for (int y = 0; y < 2; ++y)
        #pragma unroll
        for (int x = 0; x < 2; ++x) {
          m4[y][x] = fmaxf(fmaxf(m2[2*y][2*x], m2[2*y][2*x+1]),
                           fmaxf(m2[2*y+1][2*x], m2[2*y+1][2*x+1]));
          s4[vol][y][x] += m4[y][x];
        }
      float m8 = fmaxf(fmaxf(m4[0][0], m4[0][1]), fmaxf(m4[1][0], m4[1][1]));
      s8[vol] += m8;
      float m16 = m8;
      m16 = fmaxf(m16, __shfl_xor(m16, 1, 64));
      m16 = fmaxf(m16, __shfl_xor(m16, 16, 64));
      s16[vol] += m16;
      float m32 = m16;
      m32 = fmaxf(m32, __shfl_xor(m32, 2, 64));
      m32 = fmaxf(m32, __shfl_xor(m32, 32, 64));
      s32[vol] += m32;
    }
  }

  const float w0 = 1.f/(5.f*8.f*64.f*64.f);
  const float w1 = 1.f/(5.f*8.f*32.f*32.f);
  const float w2 = 1.f/(5.f*8.f*16.f*16.f);
  const float w3 = 1.f/(5.f*8.f*8.f*8.f);
  const float w4 = 1.f/(5.f*8.f*4.f*4.f);

  float l0 = 0.f;
  #pragma unroll
  for (int y = 0; y < 4; ++y)
    #pragma unroll
    for (int x = 0; x < 4; ++x) l0 += fabsf(s2[1][y][x] - s2[0][y][x]);
  float l1 = 0.f;
  #pragma unroll
  for (int y = 0; y < 2; ++y)
    #pragma unroll
    for (int x = 0; x < 2; ++x) l1 += fabsf(s4[1][y][x] - s4[0][y][x]);
  float part = l0*w0 + l1*w1 + fabsf(s8[1] - s8[0])*w2;
  if ((tid & 0x11) == 0) part += fabsf(s16[1] - s16[0])*w3;
  if ((tid & 0x33) == 0) part += fabsf(s32[1] - s32[0])*w4;

  #pragma unroll
  for (int m = 32; m >= 1; m >>= 1) part += __shfl_xor(part, m, 64);
  __shared__ float red[4];
  const int wid = tid >> 6;
  if ((tid & 63) == 0) red[wid] = part;
  __syncthreads();
  if (tid == 0) atomicAdd(ws + ACC_LOSS, red[0] + red[1] + red[2] + red[3]);
}

// Phase 3: combine.
__global__ void finalize_kernel(const float* __restrict__ ws, float* __restrict__ out)
{
  if (threadIdx.x == 0) {
    float dsum = 0.f;
    for (int b = 0; b < B; ++b) {
      const float at = ws[ACC_DICE + b*3 + 0];
      const float aa = ws[ACC_DICE + b*3 + 1];
      const float tt = ws[ACC_DICE + b*3 + 2];
      dsum += (2.f*at + 1e-6f) / (aa + tt);
    }
    out[0] = ws[ACC_LOSS] + (1.f - dsum / (float)B);
  }
}

extern "C" void kernel_launch(void* const* d_in, const int* in_sizes, int n_in,
                              void* d_out, int out_size, void* d_ws, size_t ws_size,
                              hipStream_t stream)
{
  const float* gin = (const float*)d_in[0];
  const float* gtg = (const float*)d_in[1];
  float* ws  = (float*)d_ws;
  float* out = (float*)d_out;

  hipMemsetAsync(d_ws, 0, MEMSET_BYTES, stream);

  dim3 g1(4, 16, B);
  proj_dice_kernel<<<g1, dim3(1024), 0, stream>>>(gin, gtg, ws);

  pool_loss_kernel<<<B, dim3(256), 0, stream>>>(ws);

  finalize_kernel<<<1, 64, 0, stream>>>(ws, out);
}

// Round 5
// 53.022 us; speedup vs baseline: 2.1182x; 2.1182x over previous
//
#include <hip/hip_runtime.h>

#define S 128
#define SS (S*S)
#define B 8
#define BSS (B*SS)              // 131072 floats per [b][128][128] stack
#define NEG_INF (-3.402823466e+38f)

// ws layout (float elements). NO atomics on maps — plain stores + reduce pass.
// ACC_LOSS: topo accumulator (1) + pad
// ACC_DICE: [b][{at,aa,tt}] (24)
// PA : [vol][b][i][j]  exact   (2*BSS)
// PBF: [vol][b][j][k]  final   (2*BSS)
// PCF: [vol][b][i][k]  final   (2*BSS)
// PBP: [vol][b][ic=8][j][k] partials (16*BSS)
// PCP: [vol][b][jc=4][i][k] partials (8*BSS)
#define ACC_LOSS 0
#define ACC_DICE 8
#define PA   32
#define PBF  (PA  + 2*BSS)
#define PCF  (PBF + 2*BSS)
#define PBP  (PCF + 2*BSS)
#define PCP  (PBP + 16*BSS)
#define MEMSET_BYTES 128

__device__ __forceinline__ float4 max4(float4 a, float4 b) {
  return make_float4(fmaxf(a.x,b.x), fmaxf(a.y,b.y), fmaxf(a.z,b.z), fmaxf(a.w,b.w));
}
__device__ __forceinline__ float hmax4(float4 a) {
  return fmaxf(fmaxf(a.x,a.y), fmaxf(a.z,a.w));
}
__device__ __forceinline__ float4 shflx4(float4 v, int m) {
  return make_float4(__shfl_xor(v.x,m,64), __shfl_xor(v.y,m,64),
                     __shfl_xor(v.z,m,64), __shfl_xor(v.w,m,64));
}

// Phase 1: stream channel-1 of both volumes once; projections + dice sums.
// Grid (jc=4, ic=8, b=8) = 256 blocks, 1024 threads.
// Block tile: 16 i x 32 j x 128 k. Thread = (jr = tid>>5, kl = tid&31).
// Pa exact (shuffle over k-lanes), Pb partial-in-regs -> plain store,
// Pc via LDS in 4 batches of 4 i (parity double-buffer, 4 barriers total).
__global__ __launch_bounds__(1024, 4) void proj_dice_kernel(
    const float* __restrict__ gin, const float* __restrict__ gtg,
    float* __restrict__ ws)
{
  const int jc  = blockIdx.x;   // 0..3   j chunk of 32
  const int ic  = blockIdx.y;   // 0..7   i chunk of 16
  const int b   = blockIdx.z;   // 0..7
  const int tid = threadIdx.x;
  const int jr  = tid >> 5;     // 0..31
  const int kl  = tid & 31;     // 0..31
  const int j   = (jc << 5) + jr;
  const int i0  = ic << 4;
  const int k0  = kl << 2;
  const int w   = tid >> 6;     // wave 0..15
  const int h   = (tid >> 5) & 1;

  const float* __restrict__ xin = gin + (size_t)(2*b + 1) * (size_t)(S*SS);
  const float* __restrict__ xtg = gtg + (size_t)(2*b + 1) * (size_t)(S*SS);

  float* paI = ws + PA + (size_t)(0*B + b)*SS;
  float* paT = ws + PA + (size_t)(1*B + b)*SS;
  float* pbI = ws + PBP + (size_t)((0*B + b)*8 + ic)*SS;
  float* pbT = ws + PBP + (size_t)((1*B + b)*8 + ic)*SS;
  float* pcI = ws + PCP + (size_t)((0*B + b)*4 + jc)*SS;
  float* pcT = ws + PCP + (size_t)((1*B + b)*4 + jc)*SS;

  // [parity][q][tensor][wave][k] = 128 KB
  __shared__ float lpc[2][4][2][16][S];
  __shared__ float dred[16][3];

  float4 pba = make_float4(NEG_INF, NEG_INF, NEG_INF, NEG_INF);
  float4 pbt = pba;
  float s_at = 0.f, s_aa = 0.f, s_tt = 0.f;

  for (int r = 0; r < 4; ++r) {
    const int par = r & 1;
    #pragma unroll
    for (int q = 0; q < 4; ++q) {
      const int i = i0 + (r << 2) + q;
      const size_t off = (size_t)i*SS + (size_t)j*S + k0;
      const float4 a = *(const float4*)(xin + off);
      const float4 t = *(const float4*)(xtg + off);

      s_at = fmaf(a.x,t.x, fmaf(a.y,t.y, fmaf(a.z,t.z, fmaf(a.w,t.w, s_at))));
      s_aa = fmaf(a.x,a.x, fmaf(a.y,a.y, fmaf(a.z,a.z, fmaf(a.w,a.w, s_aa))));
      s_tt = fmaf(t.x,t.x, fmaf(t.y,t.y, fmaf(t.z,t.z, fmaf(t.w,t.w, s_tt))));

      // Pb accumulate over i (register)
      pba = max4(pba, a);
      pbt = max4(pbt, t);

      // Pa[i][j]: max over k = 32 kl lanes of this half-wave
      float rma = hmax4(a), rmt = hmax4(t);
      #pragma unroll
      for (int m = 16; m >= 1; m >>= 1) {
        rma = fmaxf(rma, __shfl_xor(rma, m, 64));
        rmt = fmaxf(rmt, __shfl_xor(rmt, m, 64));
      }
      if (kl == 0) { paI[i*S + j] = rma; paT[i*S + j] = rmt; }

      // Pc wave partial: combine the wave's jr-pair, stash in LDS
      const float4 pca = max4(a, shflx4(a, 32));
      const float4 pct = max4(t, shflx4(t, 32));
      if (h == 0) {
        *(float4*)&lpc[par][q][0][w][k0] = pca;
        *(float4*)&lpc[par][q][1][w][k0] = pct;
      }
    }
    __syncthreads();
    {
      // tail: 1024 threads = 4 q x 2 tensors x 128 k -> plain store partial
      const int q  = tid >> 8;
      const int t  = (tid >> 7) & 1;
      const int k  = tid & 127;
      float m = lpc[par][q][t][0][k];
      #pragma unroll
      for (int rr = 1; rr < 16; ++rr) m = fmaxf(m, lpc[par][q][t][rr][k]);
      const int i = i0 + (r << 2) + q;
      (t ? pcT : pcI)[i*S + k] = m;
    }
    // no second barrier: next round writes the other parity half; the round
    // r+1 barrier orders reuse of this half at round r+2.
  }

  // flush Pb partial [j][k] (max over this block's 16 i's) — plain float4 store
  *(float4*)(pbI + j*S + k0) = pba;
  *(float4*)(pbT + j*S + k0) = pbt;

  // dice reduction
  float v0 = s_at, v1 = s_aa, v2 = s_tt;
  #pragma unroll
  for (int m = 32; m >= 1; m >>= 1) {
    v0 += __shfl_xor(v0, m, 64);
    v1 += __shfl_xor(v1, m, 64);
    v2 += __shfl_xor(v2, m, 64);
  }
  if ((tid & 63) == 0) { dred[w][0] = v0; dred[w][1] = v1; dred[w][2] = v2; }
  __syncthreads();
  if (tid == 0) {
    float a0 = 0.f, a1 = 0.f, a2 = 0.f;
    #pragma unroll
    for (int rr = 0; rr < 16; ++rr) { a0 += dred[rr][0]; a1 += dred[rr][1]; a2 += dred[rr][2]; }
    atomicAdd(ws + ACC_DICE + b*3 + 0, a0);
    atomicAdd(ws + ACC_DICE + b*3 + 1, a1);
    atomicAdd(ws + ACC_DICE + b*3 + 2, a2);
  }
}

// Phase 1.5: finish Pb (max over 8 ic partials) and Pc (max over 4 jc partials).
// 512 blocks x 256 threads = 131072 threads, one float4 quad each.
__global__ __launch_bounds__(256) void reduce_maps_kernel(float* __restrict__ ws)
{
  const int g = blockIdx.x * 256 + threadIdx.x;
  if (g < 65536) {
    const int vb  = g >> 12;       // vol*8+b, 0..15
    const int rem = g & 4095;      // quad within 128x128 plane
    const float4* src = (const float4*)(ws + PBP) + (size_t)vb*8*(SS/4) + rem;
    float4 m = src[0];
    #pragma unroll
    for (int p = 1; p < 8; ++p) m = max4(m, src[(size_t)p*(SS/4)]);
    ((float4*)(ws + PBF))[(size_t)vb*(SS/4) + rem] = m;
  } else {
    const int g2  = g - 65536;
    const int vb  = g2 >> 12;
    const int rem = g2 & 4095;
    const float4* src = (const float4*)(ws + PCP) + (size_t)vb*4*(SS/4) + rem;
    float4 m = src[0];
    #pragma unroll
    for (int p = 1; p < 4; ++p) m = max4(m, src[(size_t)p*(SS/4)]);
    ((float4*)(ws + PCF))[(size_t)vb*(SS/4) + rem] = m;
  }
}

// Phase 2: pyramid max-pool at all 5 scales in one pass.
// One block per batch b; thread grid 16x16, each thread owns an 8x8 tile.
__global__ __launch_bounds__(256) void pool_loss_kernel(float* __restrict__ ws)
{
  const int b   = blockIdx.x;
  const int tid = threadIdx.x;
  const int tr  = tid >> 4;
  const int tc  = tid & 15;
  const int r0  = tr << 3;
  const int c0  = tc << 3;

  float s2[2][4][4];
  float s4[2][2][2];
  float s8[2], s16[2], s32[2];
  #pragma unroll
  for (int v = 0; v < 2; ++v) {
    #pragma unroll
    for (int y = 0; y < 4; ++y)
      #pragma unroll
      for (int x = 0; x < 4; ++x) s2[v][y][x] = 0.f;
    #pragma unroll
    for (int y = 0; y < 2; ++y)
      #pragma unroll
      for (int x = 0; x < 2; ++x) s4[v][y][x] = 0.f;
    s8[v] = 0.f; s16[v] = 0.f; s32[v] = 0.f;
  }

  #pragma unroll
  for (int t = 0; t < 3; ++t) {
    #pragma unroll
    for (int vol = 0; vol < 2; ++vol) {
      const size_t region = (t == 0) ? PA : (t == 1) ? PBF : PCF;
      const float* m = ws + region + (size_t)(vol*B + b)*SS;
      float tile[8][8];
      #pragma unroll
      for (int r = 0; r < 8; ++r) {
        const float4 a = *(const float4*)(m + (size_t)(r0 + r)*S + c0);
        const float4 c = *(const float4*)(m + (size_t)(r0 + r)*S + c0 + 4);
        tile[r][0]=a.x; tile[r][1]=a.y; tile[r][2]=a.z; tile[r][3]=a.w;
        tile[r][4]=c.x; tile[r][5]=c.y; tile[r][6]=c.z; tile[r][7]=c.w;
      }
      float m2[4][4];
      #pragma unroll
      for (int y = 0; y < 4; ++y)
        #pragma unroll
        for (int x = 0; x < 4; ++x) {
          m2[y][x] = fmaxf(fmaxf(tile[2*y][2*x], tile[2*y][2*x+1]),
                           fmaxf(tile[2*y+1][2*x], tile[2*y+1][2*x+1]));
          s2[vol][y][x] += m2[y][x];
        }
      float m4[2][2];
      #pragma unroll
      for (int y = 0; y < 2; ++y)
        #pragma unroll
        for (int x = 0; x < 2; ++x) {
          m4[y][x] = fmaxf(fmaxf(m2[2*y][2*x], m2[2*y][2*x+1]),
                           fmaxf(m2[2*y+1][2*x], m2[2*y+1][2*x+1]));
          s4[vol][y][x] += m4[y][x];
        }
      float m8 = fmaxf(fmaxf(m4[0][0], m4[0][1]), fmaxf(m4[1][0], m4[1][1]));
      s8[vol] += m8;
      float m16 = m8;
      m16 = fmaxf(m16, __shfl_xor(m16, 1, 64));
      m16 = fmaxf(m16, __shfl_xor(m16, 16, 64));
      s16[vol] += m16;
      float m32 = m16;
      m32 = fmaxf(m32, __shfl_xor(m32, 2, 64));
      m32 = fmaxf(m32, __shfl_xor(m32, 32, 64));
      s32[vol] += m32;
    }
  }

  const float w0 = 1.f/(5.f*8.f*64.f*64.f);
  const float w1 = 1.f/(5.f*8.f*32.f*32.f);
  const float w2 = 1.f/(5.f*8.f*16.f*16.f);
  const float w3 = 1.f/(5.f*8.f*8.f*8.f);
  const float w4 = 1.f/(5.f*8.f*4.f*4.f);

  float l0 = 0.f;
  #pragma unroll
  for (int y = 0; y < 4; ++y)
    #pragma unroll
    for (int x = 0; x < 4; ++x) l0 += fabsf(s2[1][y][x] - s2[0][y][x]);
  float l1 = 0.f;
  #pragma unroll
  for (int y = 0; y < 2; ++y)
    #pragma unroll
    for (int x = 0; x < 2; ++x) l1 += fabsf(s4[1][y][x] - s4[0][y][x]);
  float part = l0*w0 + l1*w1 + fabsf(s8[1] - s8[0])*w2;
  if ((tid & 0x11) == 0) part += fabsf(s16[1] - s16[0])*w3;
  if ((tid & 0x33) == 0) part += fabsf(s32[1] - s32[0])*w4;

  #pragma unroll
  for (int m = 32; m >= 1; m >>= 1) part += __shfl_xor(part, m, 64);
  __shared__ float red[4];
  const int wid = tid >> 6;
  if ((tid & 63) == 0) red[wid] = part;
  __syncthreads();
  if (tid == 0) atomicAdd(ws + ACC_LOSS, red[0] + red[1] + red[2] + red[3]);
}

// Phase 3: combine.
__global__ void finalize_kernel(const float* __restrict__ ws, float* __restrict__ out)
{
  if (threadIdx.x == 0) {
    float dsum = 0.f;
    for (int b = 0; b < B; ++b) {
      const float at = ws[ACC_DICE + b*3 + 0];
      const float aa = ws[ACC_DICE + b*3 + 1];
      const float tt = ws[ACC_DICE + b*3 + 2];
      dsum += (2.f*at + 1e-6f) / (aa + tt);
    }
    out[0] = ws[ACC_LOSS] + (1.f - dsum / (float)B);
  }
}

extern "C" void kernel_launch(void* const* d_in, const int* in_sizes, int n_in,
                              void* d_out, int out_size, void* d_ws, size_t ws_size,
                              hipStream_t stream)
{
  const float* gin = (const float*)d_in[0];
  const float* gtg = (const float*)d_in[1];
  float* ws  = (float*)d_ws;
  float* out = (float*)d_out;

  hipMemsetAsync(d_ws, 0, MEMSET_BYTES, stream);

  dim3 g1(4, 8, B);
  proj_dice_kernel<<<g1, dim3(1024), 0, stream>>>(gin, gtg, ws);

  reduce_maps_kernel<<<512, dim3(256), 0, stream>>>(ws);

  pool_loss_kernel<<<B, dim3(256), 0, stream>>>(ws);

  finalize_kernel<<<1, 64, 0, stream>>>(ws, out);
}